// Round 9
// baseline (251.074 us; speedup 1.0000x reference)
//
#include <hip/hip_runtime.h>

#define NBOX   32
#define NCH    32
#define IMG    256
#define CROPH  28
#define OUTHW  224
#define TSTR   257   // LDS tile row stride (28x257 floats = 28.8 KB)

typedef float f4 __attribute__((ext_vector_type(4)));

// ===========================================================================
// Lane-exact scalar emulation of x86-simd-sort (numpy >=2.x vendored,
// xss_network_keyvaluesort.hpp) avx512 argsort for N=32 int64 keys.
// PROVEN in R4 — do not touch. Tie rules: cmp_merge keeps own index on
// equality; COEX min<-first operand's index, max<-second's.
// ===========================================================================
__device__ __forceinline__ void xss_stage(long long* k, int* a,
                                          const int* p, int mask) {
  long long nk[8]; int na[8];
  for (int j = 0; j < 8; ++j) {
    long long kb = k[p[j]]; int ab = a[p[j]];
    long long mn = (kb < k[j]) ? kb : k[j];
    long long mx = (kb < k[j]) ? k[j] : kb;
    long long sel = ((mask >> j) & 1) ? mx : mn;
    na[j] = (sel == k[j]) ? a[j] : ab;
    nk[j] = sel;
  }
  for (int j = 0; j < 8; ++j) { k[j] = nk[j]; a[j] = na[j]; }
}
__device__ __forceinline__ void xss_rev(long long* k, int* a) {
  for (int j = 0; j < 4; ++j) {
    long long tk = k[j]; k[j] = k[7-j]; k[7-j] = tk;
    int ta = a[j]; a[j] = a[7-j]; a[7-j] = ta;
  }
}
__device__ __forceinline__ void xss_coex(long long* k1, int* a1,
                                         long long* k2, int* a2) {
  for (int j = 0; j < 8; ++j) {
    long long ka = k1[j], kb = k2[j];
    int aa = a1[j], ab = a2[j];
    bool alem = (ka <= kb);
    k1[j] = alem ? ka : kb;  a1[j] = alem ? aa : ab;
    k2[j] = alem ? kb : ka;  a2[j] = alem ? ab : aa;
  }
}
__device__ __forceinline__ void xss_sort8(long long* k, int* a) {
  const int P1[8] = {1,0,3,2,5,4,7,6};
  const int P2[8] = {2,3,0,1,6,7,4,5};
  const int P3[8] = {3,2,1,0,7,6,5,4};
  const int P7[8] = {7,6,5,4,3,2,1,0};
  xss_stage(k, a, P1, 0xAA);
  xss_stage(k, a, P3, 0xCC);
  xss_stage(k, a, P1, 0xAA);
  xss_stage(k, a, P7, 0xF0);
  xss_stage(k, a, P2, 0xCC);
  xss_stage(k, a, P1, 0xAA);
}
__device__ __forceinline__ void xss_merge8(long long* k, int* a) {
  const int P1[8] = {1,0,3,2,5,4,7,6};
  const int P2[8] = {2,3,0,1,6,7,4,5};
  const int P4[8] = {4,5,6,7,0,1,2,3};
  xss_stage(k, a, P4, 0xF0);
  xss_stage(k, a, P2, 0xCC);
  xss_stage(k, a, P1, 0xAA);
}
__device__ __forceinline__ void xss_merge_pair(long long* kA, int* aA,
                                               long long* kB, int* aB) {
  xss_rev(kB, aB);
  xss_coex(kA, aA, kB, aB);
  xss_rev(kB, aB);
  xss_merge8(kA, aA);
  xss_merge8(kB, aB);
}

// ---------------------------------------------------------------------------
// Single fused kernel: per-block redundant prep (cheap, removes a launch and
// the d_ws round-trip) + R6's proven warp+resize structure.
// Grid (32,32) = 1024 blocks, 256 thr; LDS 28.8 KB -> 4-5 blocks/CU.
// ---------------------------------------------------------------------------
__global__ __launch_bounds__(256)
void fused_all(const float* __restrict__ feat,
               const int* __restrict__ boxes_raw,
               float* __restrict__ out) {
  __shared__ float tile[CROPH][TSTR];
  __shared__ int   s_w[NBOX];
  __shared__ int   s_i64, s_maxw, s_wd;
  __shared__ float s_th[4];

  int c = blockIdx.x, n = blockIdx.y;
  int tid = threadIdx.x;

  // ---- prep phase (redundant per block, ~2 µs, concurrent everywhere) ----
  if (tid < 64) {   // wave 0: int64-upload detect via ballot over odd slots
    int v = boxes_raw[2*tid + 1];
    unsigned long long b = __ballot(v != 0);
    if (tid == 0) s_i64 = (b == 0ULL) ? 1 : 0;
  }
  __syncthreads();
  bool i64mode = (s_i64 != 0);

  if (tid < NBOX) {
    int x1, y1, x3, y3;
    if (i64mode) {
      x1 = boxes_raw[(tid*4+0)*2]; y1 = boxes_raw[(tid*4+1)*2];
      x3 = boxes_raw[(tid*4+2)*2]; y3 = boxes_raw[(tid*4+3)*2];
    } else {
      x1 = boxes_raw[tid*4+0]; y1 = boxes_raw[tid*4+1];
      x3 = boxes_raw[tid*4+2]; y3 = boxes_raw[tid*4+3];
    }
    int bw = x3 > x1 ? x3-x1 : x1-x3;
    int bh = y3 > y1 ? y3-y1 : y1-y3;
    int bmax = bw > bh ? bw : bh;
    int bmin = bw > bh ? bh : bw;
    if (bmin < 1) bmin = 1;
    int wb = (CROPH*bmax + bmin - 1) / bmin;   // ceil(28*box_w/box_h)
    if (wb > IMG) wb = IMG;
    s_w[tid] = wb;
  }
  __syncthreads();

  if (tid == 0) {
    long long K[4][8]; int A[4][8];
    for (int v = 0; v < 4; ++v)
      for (int j = 0; j < 8; ++j) {
        A[v][j] = 8*v + j;
        K[v][j] = (long long)s_w[8*v + j];
      }
    for (int v = 0; v < 4; ++v) xss_sort8(K[v], A[v]);
    xss_merge_pair(K[0], A[0], K[1], A[1]);
    xss_merge_pair(K[2], A[2], K[3], A[3]);
    xss_rev(K[3], A[3]); xss_coex(K[0], A[0], K[3], A[3]); xss_rev(K[3], A[3]);
    xss_rev(K[2], A[2]); xss_coex(K[1], A[1], K[2], A[2]); xss_rev(K[2], A[2]);
    xss_coex(K[0], A[0], K[1], A[1]);
    xss_coex(K[2], A[2], K[3], A[3]);
    for (int v = 0; v < 4; ++v) xss_merge8(K[v], A[v]);

    // this block's slot n <- original box asc[31-n]
    int flat = NBOX-1-n;
    int src = A[flat >> 3][flat & 7];

    int maxw = 0;
    for (int i = 0; i < NBOX; ++i) if (s_w[i] > maxw) maxw = s_w[i];
    s_maxw = maxw;
    s_wd   = s_w[src];

    int x1, y1, x3, y3;
    if (i64mode) {
      x1 = boxes_raw[(src*4+0)*2]; y1 = boxes_raw[(src*4+1)*2];
      x3 = boxes_raw[(src*4+2)*2]; y3 = boxes_raw[(src*4+3)*2];
    } else {
      x1 = boxes_raw[src*4+0]; y1 = boxes_raw[src*4+1];
      x3 = boxes_raw[src*4+2]; y3 = boxes_raw[src*4+3];
    }
    double a = (double)(x3-x1) / (double)s_w[src];
    double e = (double)(y3-y1) / (double)CROPH;
    s_th[0] = (float)a;
    s_th[1] = (float)((double)x1 * (2.0/(double)IMG) + a - 1.0);
    s_th[2] = (float)e;
    s_th[3] = (float)((double)y1 * (2.0/(double)IMG) + e - 1.0);
  }
  __syncthreads();

  int maxw  = s_maxw;
  int width = s_wd;
  float t00 = s_th[0], t02 = s_th[1], t11 = s_th[2], t12 = s_th[3];

  // ---- stage crop tile (R6-proven) ----
  const float* fc = feat + (size_t)c*IMG*IMG;
  int w = tid;                          // 0..255
  if (w < width) {
    float gx = -1.f + (2.f/255.f)*(float)w;
    float ix = (t00*gx + t02 + 1.f)*127.5f;
    float xf = floorf(ix);
    int   x0 = (int)xf;
    x0 = min(max(x0, 0), IMG-2);        // never binds (coords interior)
    float wx = ix - xf;
    const float* col = fc + x0;
    for (int h = 0; h < CROPH; ++h) {
      float gy = -1.f + (2.f/255.f)*(float)h;
      float iy = (t11*gy + t12 + 1.f)*127.5f;
      float yf = floorf(iy);
      int   y0 = (int)yf;
      y0 = min(max(y0, 0), IMG-2);
      float wy = iy - yf;
      const float* r0 = col + y0*IMG;
      float a0 = r0[0],   a1 = r0[1];
      float b0 = r0[IMG], b1 = r0[IMG+1];
      float ta = a0 + wx*(a1-a0);
      float tb = b0 + wx*(b1-b0);
      tile[h][w] = ta + wy*(tb-ta);
    }
  } else {
    for (int h = 0; h < CROPH; ++h) tile[h][w] = 0.f;
  }
  __syncthreads();

  // ---- resize 28 x maxw -> 224 x 224 (R6-proven mapping, NT stores) ----
  int wave = tid >> 6;                  // 0..3
  int lane = tid & 63;                  // 0..63
  if (lane < OUTHW/4) {                 // 56 active lanes
    int qb = lane * 4;
    const float xs = (float)(maxw-1)/(float)(OUTHW-1);
    float tx[4]; int xi[4];
#pragma unroll
    for (int j = 0; j < 4; ++j) {
      float qx = (float)(qb+j) * xs;
      float xf = floorf(qx);
      int x = (int)xf; if (x > maxw-2) x = maxw-2;
      xi[j] = x; tx[j] = qx - (float)x;
    }
    const float pys = (float)(CROPH-1)/(float)(OUTHW-1);
    float* op = out + ((size_t)(n*NCH + c))*OUTHW*OUTHW + qb;

    int cur = -2;
    float vtop[4], vbot[4];
    for (int p = wave; p < OUTHW; p += 4) {
      float py = (float)p * pys;
      int h0 = (int)py; if (h0 > CROPH-2) h0 = CROPH-2;
      float ty = py - (float)h0;
      if (h0 != cur) {
        if (h0 == cur+1) {
#pragma unroll
          for (int j = 0; j < 4; ++j) vtop[j] = vbot[j];
        } else {
#pragma unroll
          for (int j = 0; j < 4; ++j) {
            float a0 = tile[h0][xi[j]], a1 = tile[h0][xi[j]+1];
            vtop[j] = a0 + tx[j]*(a1-a0);
          }
        }
#pragma unroll
        for (int j = 0; j < 4; ++j) {
          float b0 = tile[h0+1][xi[j]], b1 = tile[h0+1][xi[j]+1];
          vbot[j] = b0 + tx[j]*(b1-b0);
        }
        cur = h0;
      }
      f4 o;
      o.x = vtop[0] + ty*(vbot[0]-vtop[0]);
      o.y = vtop[1] + ty*(vbot[1]-vtop[1]);
      o.z = vtop[2] + ty*(vbot[2]-vtop[2]);
      o.w = vtop[3] + ty*(vbot[3]-vtop[3]);
      __builtin_nontemporal_store(o, (f4*)(op + (size_t)p*OUTHW));
    }
  }
}

// ---------------------------------------------------------------------------
extern "C" void kernel_launch(void* const* d_in, const int* in_sizes, int n_in,
                              void* d_out, int out_size, void* d_ws, size_t ws_size,
                              hipStream_t stream) {
  const float* feat  = (const float*)d_in[0];
  const int*   boxes = (const int*)d_in[1];
  float* out = (float*)d_out;
  (void)d_ws; (void)ws_size;

  fused_all<<<dim3(NCH, NBOX), 256, 0, stream>>>(feat, boxes, out);
}

// Round 10
// 234.922 us; speedup vs baseline: 1.0688x; 1.0688x over previous
//
#include <hip/hip_runtime.h>

#define NBOX   32
#define NCH    32
#define IMG    256
#define CROPH  28
#define OUTHW  224
#define TSTR   257   // LDS tile row stride (28x257 floats = 28.8 KB)

typedef float f4 __attribute__((ext_vector_type(4)));

// ===========================================================================
// Lane-exact scalar emulation of x86-simd-sort (numpy >=2.x vendored,
// xss_network_keyvaluesort.hpp) avx512 argsort for N=32 int64 keys.
// PROVEN in R4 — do not touch. Tie rules: cmp_merge keeps own index on
// equality; COEX min<-first operand's index, max<-second's.
// ===========================================================================
__device__ __forceinline__ void xss_stage(long long* k, int* a,
                                          const int* p, int mask) {
  long long nk[8]; int na[8];
  for (int j = 0; j < 8; ++j) {
    long long kb = k[p[j]]; int ab = a[p[j]];
    long long mn = (kb < k[j]) ? kb : k[j];
    long long mx = (kb < k[j]) ? k[j] : kb;
    long long sel = ((mask >> j) & 1) ? mx : mn;
    na[j] = (sel == k[j]) ? a[j] : ab;
    nk[j] = sel;
  }
  for (int j = 0; j < 8; ++j) { k[j] = nk[j]; a[j] = na[j]; }
}
__device__ __forceinline__ void xss_rev(long long* k, int* a) {
  for (int j = 0; j < 4; ++j) {
    long long tk = k[j]; k[j] = k[7-j]; k[7-j] = tk;
    int ta = a[j]; a[j] = a[7-j]; a[7-j] = ta;
  }
}
__device__ __forceinline__ void xss_coex(long long* k1, int* a1,
                                         long long* k2, int* a2) {
  for (int j = 0; j < 8; ++j) {
    long long ka = k1[j], kb = k2[j];
    int aa = a1[j], ab = a2[j];
    bool alem = (ka <= kb);
    k1[j] = alem ? ka : kb;  a1[j] = alem ? aa : ab;
    k2[j] = alem ? kb : ka;  a2[j] = alem ? ab : aa;
  }
}
__device__ __forceinline__ void xss_sort8(long long* k, int* a) {
  const int P1[8] = {1,0,3,2,5,4,7,6};
  const int P2[8] = {2,3,0,1,6,7,4,5};
  const int P3[8] = {3,2,1,0,7,6,5,4};
  const int P7[8] = {7,6,5,4,3,2,1,0};
  xss_stage(k, a, P1, 0xAA);
  xss_stage(k, a, P3, 0xCC);
  xss_stage(k, a, P1, 0xAA);
  xss_stage(k, a, P7, 0xF0);
  xss_stage(k, a, P2, 0xCC);
  xss_stage(k, a, P1, 0xAA);
}
__device__ __forceinline__ void xss_merge8(long long* k, int* a) {
  const int P1[8] = {1,0,3,2,5,4,7,6};
  const int P2[8] = {2,3,0,1,6,7,4,5};
  const int P4[8] = {4,5,6,7,0,1,2,3};
  xss_stage(k, a, P4, 0xF0);
  xss_stage(k, a, P2, 0xCC);
  xss_stage(k, a, P1, 0xAA);
}
__device__ __forceinline__ void xss_merge_pair(long long* kA, int* aA,
                                               long long* kB, int* aB) {
  xss_rev(kB, aB);
  xss_coex(kA, aA, kB, aB);
  xss_rev(kB, aB);
  xss_merge8(kA, aA);
  xss_merge8(kB, aB);
}

// ---------------------------------------------------------------------------
// Single fused kernel (R9 structure, NT stores removed — isolated A/B vs R9).
// Grid (32,32) = 1024 blocks, 256 thr; LDS 28.8 KB -> 4-5 blocks/CU.
// ---------------------------------------------------------------------------
__global__ __launch_bounds__(256)
void fused_all(const float* __restrict__ feat,
               const int* __restrict__ boxes_raw,
               float* __restrict__ out) {
  __shared__ float tile[CROPH][TSTR];
  __shared__ int   s_w[NBOX];
  __shared__ int   s_i64, s_maxw, s_wd;
  __shared__ float s_th[4];

  int c = blockIdx.x, n = blockIdx.y;
  int tid = threadIdx.x;

  // ---- prep phase (redundant per block, concurrent everywhere) ----
  if (tid < 64) {   // wave 0: int64-upload detect via ballot over odd slots
    int v = boxes_raw[2*tid + 1];
    unsigned long long b = __ballot(v != 0);
    if (tid == 0) s_i64 = (b == 0ULL) ? 1 : 0;
  }
  __syncthreads();
  bool i64mode = (s_i64 != 0);

  if (tid < NBOX) {
    int x1, y1, x3, y3;
    if (i64mode) {
      x1 = boxes_raw[(tid*4+0)*2]; y1 = boxes_raw[(tid*4+1)*2];
      x3 = boxes_raw[(tid*4+2)*2]; y3 = boxes_raw[(tid*4+3)*2];
    } else {
      x1 = boxes_raw[tid*4+0]; y1 = boxes_raw[tid*4+1];
      x3 = boxes_raw[tid*4+2]; y3 = boxes_raw[tid*4+3];
    }
    int bw = x3 > x1 ? x3-x1 : x1-x3;
    int bh = y3 > y1 ? y3-y1 : y1-y3;
    int bmax = bw > bh ? bw : bh;
    int bmin = bw > bh ? bh : bw;
    if (bmin < 1) bmin = 1;
    int wb = (CROPH*bmax + bmin - 1) / bmin;   // ceil(28*box_w/box_h)
    if (wb > IMG) wb = IMG;
    s_w[tid] = wb;
  }
  __syncthreads();

  if (tid == 0) {
    long long K[4][8]; int A[4][8];
    for (int v = 0; v < 4; ++v)
      for (int j = 0; j < 8; ++j) {
        A[v][j] = 8*v + j;
        K[v][j] = (long long)s_w[8*v + j];
      }
    for (int v = 0; v < 4; ++v) xss_sort8(K[v], A[v]);
    xss_merge_pair(K[0], A[0], K[1], A[1]);
    xss_merge_pair(K[2], A[2], K[3], A[3]);
    xss_rev(K[3], A[3]); xss_coex(K[0], A[0], K[3], A[3]); xss_rev(K[3], A[3]);
    xss_rev(K[2], A[2]); xss_coex(K[1], A[1], K[2], A[2]); xss_rev(K[2], A[2]);
    xss_coex(K[0], A[0], K[1], A[1]);
    xss_coex(K[2], A[2], K[3], A[3]);
    for (int v = 0; v < 4; ++v) xss_merge8(K[v], A[v]);

    // this block's slot n <- original box asc[31-n]
    int flat = NBOX-1-n;
    int src = A[flat >> 3][flat & 7];

    int maxw = 0;
    for (int i = 0; i < NBOX; ++i) if (s_w[i] > maxw) maxw = s_w[i];
    s_maxw = maxw;
    s_wd   = s_w[src];

    int x1, y1, x3, y3;
    if (i64mode) {
      x1 = boxes_raw[(src*4+0)*2]; y1 = boxes_raw[(src*4+1)*2];
      x3 = boxes_raw[(src*4+2)*2]; y3 = boxes_raw[(src*4+3)*2];
    } else {
      x1 = boxes_raw[src*4+0]; y1 = boxes_raw[src*4+1];
      x3 = boxes_raw[src*4+2]; y3 = boxes_raw[src*4+3];
    }
    double a = (double)(x3-x1) / (double)s_w[src];
    double e = (double)(y3-y1) / (double)CROPH;
    s_th[0] = (float)a;
    s_th[1] = (float)((double)x1 * (2.0/(double)IMG) + a - 1.0);
    s_th[2] = (float)e;
    s_th[3] = (float)((double)y1 * (2.0/(double)IMG) + e - 1.0);
  }
  __syncthreads();

  int maxw  = s_maxw;
  int width = s_wd;
  float t00 = s_th[0], t02 = s_th[1], t11 = s_th[2], t12 = s_th[3];

  // ---- stage crop tile (R6-proven) ----
  const float* fc = feat + (size_t)c*IMG*IMG;
  int w = tid;                          // 0..255
  if (w < width) {
    float gx = -1.f + (2.f/255.f)*(float)w;
    float ix = (t00*gx + t02 + 1.f)*127.5f;
    float xf = floorf(ix);
    int   x0 = (int)xf;
    x0 = min(max(x0, 0), IMG-2);        // never binds (coords interior)
    float wx = ix - xf;
    const float* col = fc + x0;
    for (int h = 0; h < CROPH; ++h) {
      float gy = -1.f + (2.f/255.f)*(float)h;
      float iy = (t11*gy + t12 + 1.f)*127.5f;
      float yf = floorf(iy);
      int   y0 = (int)yf;
      y0 = min(max(y0, 0), IMG-2);
      float wy = iy - yf;
      const float* r0 = col + y0*IMG;
      float a0 = r0[0],   a1 = r0[1];
      float b0 = r0[IMG], b1 = r0[IMG+1];
      float ta = a0 + wx*(a1-a0);
      float tb = b0 + wx*(b1-b0);
      tile[h][w] = ta + wy*(tb-ta);
    }
  } else {
    for (int h = 0; h < CROPH; ++h) tile[h][w] = 0.f;
  }
  __syncthreads();

  // ---- resize 28 x maxw -> 224 x 224 (R6-proven mapping, PLAIN stores) ----
  int wave = tid >> 6;                  // 0..3
  int lane = tid & 63;                  // 0..63
  if (lane < OUTHW/4) {                 // 56 active lanes
    int qb = lane * 4;
    const float xs = (float)(maxw-1)/(float)(OUTHW-1);
    float tx[4]; int xi[4];
#pragma unroll
    for (int j = 0; j < 4; ++j) {
      float qx = (float)(qb+j) * xs;
      float xf = floorf(qx);
      int x = (int)xf; if (x > maxw-2) x = maxw-2;
      xi[j] = x; tx[j] = qx - (float)x;
    }
    const float pys = (float)(CROPH-1)/(float)(OUTHW-1);
    float* op = out + ((size_t)(n*NCH + c))*OUTHW*OUTHW + qb;

    int cur = -2;
    float vtop[4], vbot[4];
    for (int p = wave; p < OUTHW; p += 4) {
      float py = (float)p * pys;
      int h0 = (int)py; if (h0 > CROPH-2) h0 = CROPH-2;
      float ty = py - (float)h0;
      if (h0 != cur) {
        if (h0 == cur+1) {
#pragma unroll
          for (int j = 0; j < 4; ++j) vtop[j] = vbot[j];
        } else {
#pragma unroll
          for (int j = 0; j < 4; ++j) {
            float a0 = tile[h0][xi[j]], a1 = tile[h0][xi[j]+1];
            vtop[j] = a0 + tx[j]*(a1-a0);
          }
        }
#pragma unroll
        for (int j = 0; j < 4; ++j) {
          float b0 = tile[h0+1][xi[j]], b1 = tile[h0+1][xi[j]+1];
          vbot[j] = b0 + tx[j]*(b1-b0);
        }
        cur = h0;
      }
      f4 o;
      o.x = vtop[0] + ty*(vbot[0]-vtop[0]);
      o.y = vtop[1] + ty*(vbot[1]-vtop[1]);
      o.z = vtop[2] + ty*(vbot[2]-vtop[2]);
      o.w = vtop[3] + ty*(vbot[3]-vtop[3]);
      *(f4*)(op + (size_t)p*OUTHW) = o;
    }
  }
}

// ---------------------------------------------------------------------------
extern "C" void kernel_launch(void* const* d_in, const int* in_sizes, int n_in,
                              void* d_out, int out_size, void* d_ws, size_t ws_size,
                              hipStream_t stream) {
  const float* feat  = (const float*)d_in[0];
  const int*   boxes = (const int*)d_in[1];
  float* out = (float*)d_out;
  (void)d_ws; (void)ws_size;

  fused_all<<<dim3(NCH, NBOX), 256, 0, stream>>>(feat, boxes, out);
}

// Round 11
// 220.265 us; speedup vs baseline: 1.1399x; 1.0665x over previous
//
#include <hip/hip_runtime.h>

#define NBOX   32
#define NCH    32
#define IMG    256
#define CROPH  28
#define OUTHW  224
#define TSTR   257   // LDS tile row stride (28x257 floats = 28.8 KB)

typedef float f4 __attribute__((ext_vector_type(4)));

// ===========================================================================
// Lane-exact scalar emulation of x86-simd-sort (numpy >=2.x vendored,
// xss_network_keyvaluesort.hpp) avx512 argsort for N=32 int64 keys.
// PROVEN in R4 — do not touch. Tie rules: cmp_merge keeps own index on
// equality; COEX min<-first operand's index, max<-second's.
// ===========================================================================
__device__ __forceinline__ void xss_stage(long long* k, int* a,
                                          const int* p, int mask) {
  long long nk[8]; int na[8];
  for (int j = 0; j < 8; ++j) {
    long long kb = k[p[j]]; int ab = a[p[j]];
    long long mn = (kb < k[j]) ? kb : k[j];
    long long mx = (kb < k[j]) ? k[j] : kb;
    long long sel = ((mask >> j) & 1) ? mx : mn;
    na[j] = (sel == k[j]) ? a[j] : ab;
    nk[j] = sel;
  }
  for (int j = 0; j < 8; ++j) { k[j] = nk[j]; a[j] = na[j]; }
}
__device__ __forceinline__ void xss_rev(long long* k, int* a) {
  for (int j = 0; j < 4; ++j) {
    long long tk = k[j]; k[j] = k[7-j]; k[7-j] = tk;
    int ta = a[j]; a[j] = a[7-j]; a[7-j] = ta;
  }
}
__device__ __forceinline__ void xss_coex(long long* k1, int* a1,
                                         long long* k2, int* a2) {
  for (int j = 0; j < 8; ++j) {
    long long ka = k1[j], kb = k2[j];
    int aa = a1[j], ab = a2[j];
    bool alem = (ka <= kb);
    k1[j] = alem ? ka : kb;  a1[j] = alem ? aa : ab;
    k2[j] = alem ? kb : ka;  a2[j] = alem ? ab : aa;
  }
}
__device__ __forceinline__ void xss_sort8(long long* k, int* a) {
  const int P1[8] = {1,0,3,2,5,4,7,6};
  const int P2[8] = {2,3,0,1,6,7,4,5};
  const int P3[8] = {3,2,1,0,7,6,5,4};
  const int P7[8] = {7,6,5,4,3,2,1,0};
  xss_stage(k, a, P1, 0xAA);
  xss_stage(k, a, P3, 0xCC);
  xss_stage(k, a, P1, 0xAA);
  xss_stage(k, a, P7, 0xF0);
  xss_stage(k, a, P2, 0xCC);
  xss_stage(k, a, P1, 0xAA);
}
__device__ __forceinline__ void xss_merge8(long long* k, int* a) {
  const int P1[8] = {1,0,3,2,5,4,7,6};
  const int P2[8] = {2,3,0,1,6,7,4,5};
  const int P4[8] = {4,5,6,7,0,1,2,3};
  xss_stage(k, a, P4, 0xF0);
  xss_stage(k, a, P2, 0xCC);
  xss_stage(k, a, P1, 0xAA);
}
__device__ __forceinline__ void xss_merge_pair(long long* kA, int* aA,
                                               long long* kB, int* aB) {
  xss_rev(kB, aB);
  xss_coex(kA, aA, kB, aB);
  xss_rev(kB, aB);
  xss_merge8(kA, aA);
  xss_merge8(kB, aB);
}

// ---------------------------------------------------------------------------
// Kernel 1: per-box params (32 lanes parallel) + lane-0 exact xss argsort
// ---------------------------------------------------------------------------
__global__ void prep_kernel(const int* __restrict__ boxes_raw,
                            int* __restrict__ wsi, float* __restrict__ th) {
  __shared__ int    s_w[NBOX];
  __shared__ double s_t[NBOX][4];
  __shared__ int    s_asc[NBOX];
  __shared__ int    s_i64;
  int lane = threadIdx.x;

  if (lane == 0) {
    int i64 = 1;
    for (int i = 1; i < NBOX*4; i += 2)
      if (boxes_raw[i] != 0) { i64 = 0; break; }
    s_i64 = i64;
  }
  __syncthreads();
  bool i64mode = (s_i64 != 0);

  if (lane < NBOX) {
    int x1, y1, x3, y3;
    if (i64mode) {
      x1 = boxes_raw[(lane*4+0)*2]; y1 = boxes_raw[(lane*4+1)*2];
      x3 = boxes_raw[(lane*4+2)*2]; y3 = boxes_raw[(lane*4+3)*2];
    } else {
      x1 = boxes_raw[lane*4+0]; y1 = boxes_raw[lane*4+1];
      x3 = boxes_raw[lane*4+2]; y3 = boxes_raw[lane*4+3];
    }
    int bw = x3 > x1 ? x3-x1 : x1-x3;
    int bh = y3 > y1 ? y3-y1 : y1-y3;
    int bmax = bw > bh ? bw : bh;
    int bmin = bw > bh ? bh : bw;
    if (bmin < 1) bmin = 1;
    int wb = (CROPH*bmax + bmin - 1) / bmin;   // ceil(28*box_w/box_h)
    if (wb > IMG) wb = IMG;
    s_w[lane] = wb;
    double a = (double)(x3-x1) / (double)wb;
    double e = (double)(y3-y1) / (double)CROPH;
    s_t[lane][0] = a;
    s_t[lane][1] = (double)x1 * (2.0/(double)IMG) + a - 1.0;
    s_t[lane][2] = e;
    s_t[lane][3] = (double)y1 * (2.0/(double)IMG) + e - 1.0;
  }
  __syncthreads();

  if (lane == 0) {
    long long K[4][8]; int A[4][8];
    for (int v = 0; v < 4; ++v)
      for (int j = 0; j < 8; ++j) {
        A[v][j] = 8*v + j;
        K[v][j] = (long long)s_w[8*v + j];
      }
    for (int v = 0; v < 4; ++v) xss_sort8(K[v], A[v]);
    xss_merge_pair(K[0], A[0], K[1], A[1]);
    xss_merge_pair(K[2], A[2], K[3], A[3]);
    xss_rev(K[3], A[3]); xss_coex(K[0], A[0], K[3], A[3]); xss_rev(K[3], A[3]);
    xss_rev(K[2], A[2]); xss_coex(K[1], A[1], K[2], A[2]); xss_rev(K[2], A[2]);
    xss_coex(K[0], A[0], K[1], A[1]);
    xss_coex(K[2], A[2], K[3], A[3]);
    for (int v = 0; v < 4; ++v) xss_merge8(K[v], A[v]);
    for (int v = 0; v < 4; ++v)
      for (int j = 0; j < 8; ++j) s_asc[8*v + j] = A[v][j];
    int maxw = 0;
    for (int i = 0; i < NBOX; ++i) if (s_w[i] > maxw) maxw = s_w[i];
    wsi[0] = maxw;
  }
  __syncthreads();

  if (lane < NBOX) {                    // order = argsort(asc)[::-1]
    int src = s_asc[NBOX-1-lane];
    wsi[1+lane]   = s_w[src];
    th[lane*4+0]  = (float)s_t[src][0];
    th[lane*4+1]  = (float)s_t[src][1];
    th[lane*4+2]  = (float)s_t[src][2];
    th[lane*4+3]  = (float)s_t[src][3];
  }
}

// ---------------------------------------------------------------------------
// Kernel 2: fused warp + resize. One block per (n,c); 28x256 crop tile in LDS
// (28.8 KB -> 4-5 blocks/CU; all 1024 blocks co-resident).
//   Stage:  thread w computes crop[h][w] for h=0..27.
//   Resize: wave v owns rows p=v,v+4,...; lane l<56 owns cols 4l..4l+3;
//           one plain f4 store per row (896 B contiguous per wave-store).
// Best measured config (R6: 220.8 µs total @ fills~127); NT stores and
// 2ch/block and in-kernel prep all regressed — keep exactly this.
// ---------------------------------------------------------------------------
__global__ __launch_bounds__(256)
void fused_kernel(const float* __restrict__ feat,
                  const int* __restrict__ wsi,
                  const float* __restrict__ th,
                  float* __restrict__ out) {
  __shared__ float tile[CROPH][TSTR];
  int c = blockIdx.x, n = blockIdx.y;
  int tid = threadIdx.x;

  int maxw  = wsi[0];
  int width = wsi[1+n];
  float t00 = th[n*4+0], t02 = th[n*4+1], t11 = th[n*4+2], t12 = th[n*4+3];

  // ---- stage crop tile ----
  const float* fc = feat + (size_t)c*IMG*IMG;
  int w = tid;                          // 0..255
  if (w < width) {
    float gx = -1.f + (2.f/255.f)*(float)w;
    float ix = (t00*gx + t02 + 1.f)*127.5f;
    float xf = floorf(ix);
    int   x0 = (int)xf;
    x0 = min(max(x0, 0), IMG-2);        // never binds (coords interior)
    float wx = ix - xf;
    const float* col = fc + x0;
    for (int h = 0; h < CROPH; ++h) {
      float gy = -1.f + (2.f/255.f)*(float)h;
      float iy = (t11*gy + t12 + 1.f)*127.5f;
      float yf = floorf(iy);
      int   y0 = (int)yf;
      y0 = min(max(y0, 0), IMG-2);
      float wy = iy - yf;
      const float* r0 = col + y0*IMG;
      float a0 = r0[0],   a1 = r0[1];
      float b0 = r0[IMG], b1 = r0[IMG+1];
      float ta = a0 + wx*(a1-a0);
      float tb = b0 + wx*(b1-b0);
      tile[h][w] = ta + wy*(tb-ta);
    }
  } else {
    for (int h = 0; h < CROPH; ++h) tile[h][w] = 0.f;
  }
  __syncthreads();

  // ---- resize 28 x maxw -> 224 x 224, bilinear align_corners=True ----
  int wave = tid >> 6;                  // 0..3
  int lane = tid & 63;                  // 0..63
  if (lane < OUTHW/4) {                 // 56 active lanes
    int qb = lane * 4;
    const float xs = (float)(maxw-1)/(float)(OUTHW-1);
    float tx[4]; int xi[4];
#pragma unroll
    for (int j = 0; j < 4; ++j) {
      float qx = (float)(qb+j) * xs;
      float xf = floorf(qx);
      int x = (int)xf; if (x > maxw-2) x = maxw-2;
      xi[j] = x; tx[j] = qx - (float)x;
    }
    const float pys = (float)(CROPH-1)/(float)(OUTHW-1);
    float* op = out + ((size_t)(n*NCH + c))*OUTHW*OUTHW + qb;

    int cur = -2;
    float vtop[4], vbot[4];
    for (int p = wave; p < OUTHW; p += 4) {
      float py = (float)p * pys;
      int h0 = (int)py; if (h0 > CROPH-2) h0 = CROPH-2;
      float ty = py - (float)h0;
      if (h0 != cur) {
        if (h0 == cur+1) {
#pragma unroll
          for (int j = 0; j < 4; ++j) vtop[j] = vbot[j];
        } else {
#pragma unroll
          for (int j = 0; j < 4; ++j) {
            float a0 = tile[h0][xi[j]], a1 = tile[h0][xi[j]+1];
            vtop[j] = a0 + tx[j]*(a1-a0);
          }
        }
#pragma unroll
        for (int j = 0; j < 4; ++j) {
          float b0 = tile[h0+1][xi[j]], b1 = tile[h0+1][xi[j]+1];
          vbot[j] = b0 + tx[j]*(b1-b0);
        }
        cur = h0;
      }
      f4 o;
      o.x = vtop[0] + ty*(vbot[0]-vtop[0]);
      o.y = vtop[1] + ty*(vbot[1]-vtop[1]);
      o.z = vtop[2] + ty*(vbot[2]-vtop[2]);
      o.w = vtop[3] + ty*(vbot[3]-vtop[3]);
      *(f4*)(op + (size_t)p*OUTHW) = o;
    }
  }
}

// ---------------------------------------------------------------------------
extern "C" void kernel_launch(void* const* d_in, const int* in_sizes, int n_in,
                              void* d_out, int out_size, void* d_ws, size_t ws_size,
                              hipStream_t stream) {
  const float* feat  = (const float*)d_in[0];
  const int*   boxes = (const int*)d_in[1];
  float* out = (float*)d_out;

  int*   wsi = (int*)d_ws;                    // [0]=maxw, [1..32]=sorted widths
  float* th  = (float*)((char*)d_ws + 512);   // [32][4] sorted thetas

  prep_kernel<<<1, 64, 0, stream>>>(boxes, wsi, th);
  fused_kernel<<<dim3(NCH, NBOX), 256, 0, stream>>>(feat, wsi, th, out);
}